// Round 12
// baseline (556.867 us; speedup 1.0000x reference)
//
#include <hip/hip_runtime.h>
#include <hip/hip_bf16.h>
#include <cstdint>
#include <cstddef>

// Qwen3 MoE layer: T=2048 tokens, H=1024 hidden, E=64 experts, I=768, top-K=8
#define T_TOK 2048
#define H_DIM 1024
#define E_NUM 64
#define I_DIM 768
#define K_TOP 8

typedef __attribute__((ext_vector_type(8))) __bf16 bf16x8;
typedef __attribute__((ext_vector_type(8))) unsigned short u16x8;
typedef __attribute__((ext_vector_type(4))) float f32x4;
typedef unsigned short ushort_t;

__device__ __forceinline__ unsigned short f2bf(float f) {
  uint32_t u = __builtin_bit_cast(uint32_t, f);
  u += 0x7fffu + ((u >> 16) & 1u);
  return (unsigned short)(u >> 16);
}

__device__ __forceinline__ u16x8 cvt8b(f32x4 a, f32x4 b) {
  bf16x8 r;
  r[0] = (__bf16)a[0]; r[1] = (__bf16)a[1]; r[2] = (__bf16)a[2]; r[3] = (__bf16)a[3];
  r[4] = (__bf16)b[0]; r[5] = (__bf16)b[1]; r[6] = (__bf16)b[2]; r[7] = (__bf16)b[3];
  return __builtin_bit_cast(u16x8, r);
}

// async 16B global -> LDS; dest = wave-uniform base (HW adds lane*16)
__device__ __forceinline__ void async16(const void* l, const void* g) {
  __builtin_amdgcn_global_load_lds(
      (const __attribute__((address_space(1))) unsigned int*)g,
      (__attribute__((address_space(3))) unsigned int*)l, 16, 0, 0);
}

// Bijective XCD-contiguous decode over the ACTIVE index space [0, n_act)
__device__ __forceinline__ int xcd_decode(int wg0, int n_act) {
  int q = n_act >> 3, r = n_act & 7;
  int xcd = wg0 & 7, rank = wg0 >> 3;
  int cnt = q + (xcd < r ? 1 : 0);
  if (rank >= cnt) return -1;
  return (xcd < r ? xcd * (q + 1) : r * (q + 1) + (xcd - r) * q) + rank;
}

// ---------------- x f32 -> bf16 pre-cast ----------------
__global__ __launch_bounds__(256) void xcast_kernel(const float* __restrict__ x,
                                                    ushort_t* __restrict__ xb) {
  int i = blockIdx.x * 256 + threadIdx.x;
  const f32x4* s = (const f32x4*)(x + (size_t)i * 8);
  *(u16x8*)(xb + (size_t)i * 8) = cvt8b(s[0], s[1]);
}

// ---------------- router: 4 tokens/block ----------------
__global__ __launch_bounds__(64) void router_kernel(
    const float* __restrict__ x, const float* __restrict__ wr,
    int* __restrict__ topk_id, float* __restrict__ topk_w,
    int* __restrict__ counts) {
  const int t0 = blockIdx.x * 4;
  const int e = threadIdx.x;
  const float4* wv = (const float4*)(wr + (size_t)e * H_DIM);
  const float4* xv0 = (const float4*)(x + (size_t)t0 * H_DIM);
  const float4* xv1 = (const float4*)(x + (size_t)(t0 + 1) * H_DIM);
  const float4* xv2 = (const float4*)(x + (size_t)(t0 + 2) * H_DIM);
  const float4* xv3 = (const float4*)(x + (size_t)(t0 + 3) * H_DIM);
  float acc0 = 0.f, acc1 = 0.f, acc2 = 0.f, acc3 = 0.f;
#pragma unroll 4
  for (int i = 0; i < H_DIM / 4; ++i) {
    float4 b = wv[i];
    float4 a0 = xv0[i], a1 = xv1[i], a2 = xv2[i], a3 = xv3[i];
    acc0 = fmaf(a0.x, b.x, fmaf(a0.y, b.y, fmaf(a0.z, b.z, fmaf(a0.w, b.w, acc0))));
    acc1 = fmaf(a1.x, b.x, fmaf(a1.y, b.y, fmaf(a1.z, b.z, fmaf(a1.w, b.w, acc1))));
    acc2 = fmaf(a2.x, b.x, fmaf(a2.y, b.y, fmaf(a2.z, b.z, fmaf(a2.w, b.w, acc2))));
    acc3 = fmaf(a3.x, b.x, fmaf(a3.y, b.y, fmaf(a3.z, b.z, fmaf(a3.w, b.w, acc3))));
  }
  float accs[4] = {acc0, acc1, acc2, acc3};
#pragma unroll 1
  for (int tt = 0; tt < 4; ++tt) {
    int t = t0 + tt;
    float acc = accs[tt];
    float m = acc;
    for (int o = 32; o; o >>= 1) m = fmaxf(m, __shfl_xor(m, o));
    float p = __expf(acc - m);
    float s = p;
    for (int o = 32; o; o >>= 1) s += __shfl_xor(s, o);
    p /= s;
    float v = p;
    int sid = 0;
    float sw = 0.f;
    for (int k = 0; k < K_TOP; ++k) {
      float bv = v;
      int bi = e;
      for (int o = 32; o; o >>= 1) {
        float ov = __shfl_xor(bv, o);
        int oi = __shfl_xor(bi, o);
        if (ov > bv || (ov == bv && oi < bi)) { bv = ov; bi = oi; }
      }
      if (e == k) { sid = bi; sw = bv; }
      if (e == bi) v = -1.f;
    }
    float ssum = (e < K_TOP) ? sw : 0.f;
    for (int o = 32; o; o >>= 1) ssum += __shfl_xor(ssum, o);
    if (e < K_TOP) {
      topk_id[t * K_TOP + e] = sid;
      topk_w[t * K_TOP + e] = sw / ssum;
      atomicAdd(&counts[sid], 1);
    }
  }
}

// ---------------- scan: offsets + tile list (BM=256, max 2 tiles/expert) ----------------
__global__ __launch_bounds__(64) void scan_kernel(
    const int* __restrict__ counts, int* __restrict__ offsets,
    int* __restrict__ cursor, int* __restrict__ tile_list,
    int* __restrict__ n_tiles) {
  int e = threadIdx.x;
  int ne = counts[e];
  int x = ne;
  for (int o = 1; o < 64; o <<= 1) {
    int v = __shfl_up(x, o);
    if (e >= o) x += v;
  }
  int excl = x - ne;
  offsets[e] = excl;
  cursor[e] = excl;
  int ntl = (ne + 255) >> 8;
  if (ntl > 2) ntl = 2;
  int y2 = ntl;
  for (int o = 1; o < 64; o <<= 1) {
    int v = __shfl_up(y2, o);
    if (e >= o) y2 += v;
  }
  int texcl = y2 - ntl;
  for (int m = 0; m < ntl; ++m) tile_list[texcl + m] = (e << 2) | m;
  if (e == 63) *n_tiles = texcl + ntl;
}

__global__ __launch_bounds__(256) void build_kernel(
    const int* __restrict__ topk_id, const float* __restrict__ topk_w,
    int* __restrict__ cursor, int* __restrict__ pair_token, float* __restrict__ pair_w) {
  int i = blockIdx.x * 256 + threadIdx.x;
  int t = i >> 3;
  int e = topk_id[i];
  int pos = atomicAdd(&cursor[e], 1);
  pair_token[pos] = t;
  pair_w[pos] = topk_w[i];
}

// LDS tiles: rows of 32 bf16 = 4 chunks of 16B; chunk slot = c ^ ((row>>1)&3)
// (2-way max conflict on frag reads: banks 16*(row&1) + 4*slot)

// ================= stage 1: h = silu(X Wg^T) * (X Wu^T) =================
// BM=256, B-tile = [128 G-rows ; 128 U-rows] of one 128-wide I-block, BK=32.
// 8 waves 2M x 4N (wave out 128x64). 4-phase interleave per K-tile; counted
// vmcnt(2); stage ops for t+1 spread over phases 0-2; cvt+ds_write at ph3.
#define GU_NIT 32

__global__ __launch_bounds__(512, 2) void gemm_gu_kernel(
    const ushort_t* __restrict__ xb, const float* __restrict__ wg,
    const float* __restrict__ wu, const int* __restrict__ offsets,
    const int* __restrict__ counts, const int* __restrict__ pair_token,
    const int* __restrict__ tile_list, const int* __restrict__ n_tiles,
    ushort_t* __restrict__ h_buf) {
  int idx = xcd_decode(blockIdx.x, (*n_tiles) * 6);
  if (idx < 0) return;
  int tl = idx / 6, nt = idx - tl * 6;
  int ent = tile_list[tl];
  int e = ent >> 2, mt = ent & 3;
  int ne = counts[e], off = offsets[e];
  int ib = nt * 128;
  int vr = ne - mt * 256;
  if (vr <= 0) return;
  if (vr > 256) vr = 256;

  // arena: A bufs 2x16KB @0, B bufs 2x16KB @32K, sTok @64K
  __shared__ __align__(16) char L[66560];
  ushort_t* AsB = (ushort_t*)L;          // elem idx
  ushort_t* BlB = (ushort_t*)(L + 32768);
  int* sTok = (int*)(L + 65536);

  const int tid = threadIdx.x;
  const int lane = tid & 63;
  const int wid = tid >> 6;            // 0..7
  const int wrM = wid >> 2, wrN = wid & 3;
  const int lrow = lane & 15, lk = lane >> 4;

  if (tid < 256) {
    int p = mt * 256 + tid;
    sTok[tid] = pair_token[off + (p < ne ? p : ne - 1)];
  }
  __syncthreads();

  // A DMA: 1024 chunks (2/thread); linear dest slot p; source chunk pre-swizzled
  const ushort_t* xsrc[2];
  int adst[2];
#pragma unroll
  for (int j = 0; j < 2; ++j) {
    int p = j * 512 + tid;
    int row = p >> 2, c = p & 3;
    xsrc[j] = xb + (size_t)sTok[row] * H_DIM + ((c ^ ((row >> 1) & 3)) << 3);
    adst[j] = (j * 512 + wid * 64) * 8;  // wave-uniform base (elems)
  }
  // B glb: thread covers one row's chunk pair {cs0, cs1}; write-side swizzle
  const int brow = tid >> 1;
  const int cs0 = (tid & 1) * 2, cs1 = cs0 + 1;
  const float* bq = (brow < 128)
      ? wg + ((size_t)e * I_DIM + ib + brow) * H_DIM
      : wu + ((size_t)e * I_DIM + ib + brow - 128) * H_DIM;
  const float* bsrc0 = bq + cs0 * 8;
  const float* bsrc1 = bq + cs1 * 8;
  const int bd0 = (brow * 4 + (cs0 ^ ((brow >> 1) & 3))) * 8;
  const int bd1 = (brow * 4 + (cs1 ^ ((brow >> 1) & 3))) * 8;

  const bool wact = (wrM * 128) < vr;

  f32x4 acc[8][4];
#pragma unroll
  for (int mi = 0; mi < 8; ++mi)
#pragma unroll
    for (int ni = 0; ni < 4; ++ni) acc[mi][ni] = f32x4{0.f, 0.f, 0.f, 0.f};

#define GU_ADMA(NB, K0)                                           \
  do {                                                            \
    async16(&AsB[(NB) * 8192 + adst[0]], xsrc[0] + (K0));         \
    async16(&AsB[(NB) * 8192 + adst[1]], xsrc[1] + (K0));         \
  } while (0)

#define GU_AF(AB, MI)                                                        \
  do {                                                                       \
    int R0 = wrM * 128 + (MI) * 16 + lrow;                                   \
    int R1 = R0 + 16;                                                        \
    af0 = *(const u16x8*)&AsB[(AB) * 8192 + R0 * 32 + ((lk ^ ((R0 >> 1) & 3)) << 3)]; \
    af1 = *(const u16x8*)&AsB[(AB) * 8192 + R1 * 32 + ((lk ^ ((R1 >> 1) & 3)) << 3)]; \
  } while (0)

#define GU_MFMA2(MI)                                                         \
  _Pragma("unroll") for (int ni = 0; ni < 4; ++ni) {                         \
    acc[MI][ni] = __builtin_amdgcn_mfma_f32_16x16x32_bf16(                   \
        __builtin_bit_cast(bf16x8, af0), __builtin_bit_cast(bf16x8, bf[ni]), \
        acc[MI][ni], 0, 0, 0);                                               \
    acc[(MI) + 1][ni] = __builtin_amdgcn_mfma_f32_16x16x32_bf16(             \
        __builtin_bit_cast(bf16x8, af1), __builtin_bit_cast(bf16x8, bf[ni]), \
        acc[(MI) + 1][ni], 0, 0, 0);                                         \
  }

#define FENCE_LGKM                                             \
  asm volatile("s_waitcnt lgkmcnt(0)" ::: "memory");           \
  __builtin_amdgcn_sched_barrier(0)

  // prologue: A(0) DMA; B(0) glb -> cvt -> Bl(0)
  GU_ADMA(0, 0);
  {
    f32x4 p0 = *(const f32x4*)(bsrc0), p1 = *(const f32x4*)(bsrc0 + 4);
    f32x4 p2 = *(const f32x4*)(bsrc1), p3 = *(const f32x4*)(bsrc1 + 4);
    *(u16x8*)&BlB[bd0] = cvt8b(p0, p1);
    *(u16x8*)&BlB[bd1] = cvt8b(p2, p3);
  }
  FENCE_LGKM;
  __builtin_amdgcn_s_barrier();

#pragma unroll 1
  for (int t = 0; t < GU_NIT; ++t) {
    const int b = t & 1, nb = b ^ 1;
    const int kn = (t + 1 < GU_NIT) ? (t + 1) * 32 : 0;
    u16x8 bf[4], af0, af1;
    f32x4 br0, br1, br2, br3;
    // ---- phase 0: issue B(t+1) pair 0; A(t) & B-LDS(t) ready ----
    br0 = *(const f32x4*)(bsrc0 + kn);
    br1 = *(const f32x4*)(bsrc0 + kn + 4);
    asm volatile("s_waitcnt vmcnt(2)" ::: "memory");
    __builtin_amdgcn_sched_barrier(0);
    __builtin_amdgcn_s_barrier();
    if (wact) {
#pragma unroll
      for (int ni = 0; ni < 4; ++ni) {
        int Rb = wrN * 64 + ni * 16 + lrow;
        bf[ni] = *(const u16x8*)&BlB[b * 8192 + Rb * 32 + ((lk ^ ((Rb >> 1) & 3)) << 3)];
      }
      GU_AF(b, 0);
    }
    FENCE_LGKM;
    __builtin_amdgcn_s_setprio(1);
    if (wact) { GU_MFMA2(0); }
    __builtin_amdgcn_s_setprio(0);
    __builtin_amdgcn_s_barrier();
    // ---- phase 1: issue B(t+1) pair 1 ----
    br2 = *(const f32x4*)(bsrc1 + kn);
    br3 = *(const f32x4*)(bsrc1 + kn + 4);
    if (wact) GU_AF(b, 2);
    FENCE_LGKM;
    __builtin_amdgcn_s_setprio(1);
    if (wact) { GU_MFMA2(2); }
    __builtin_amdgcn_s_setprio(0);
    __builtin_amdgcn_s_barrier();
    // ---- phase 2: issue A(t+1) DMA ----
    GU_ADMA(nb, kn);
    if (wact) GU_AF(b, 4);
    FENCE_LGKM;
    __builtin_amdgcn_s_setprio(1);
    if (wact) { GU_MFMA2(4); }
    __builtin_amdgcn_s_setprio(0);
    __builtin_amdgcn_s_barrier();
    // ---- phase 3: cvt + ds_write B(t+1) ----
    *(u16x8*)&BlB[nb * 8192 + bd0] = cvt8b(br0, br1);
    *(u16x8*)&BlB[nb * 8192 + bd1] = cvt8b(br2, br3);
    if (wact) GU_AF(b, 6);
    FENCE_LGKM;
    __builtin_amdgcn_s_setprio(1);
    if (wact) { GU_MFMA2(6); }
    __builtin_amdgcn_s_setprio(0);
    __builtin_amdgcn_s_barrier();
  }
#undef GU_ADMA
#undef GU_AF
#undef GU_MFMA2

  // ---- epilogue: cross-wave SwiGLU via f32 LDS exchange (2 rounds) ----
  float* ex = (float*)L;  // 64 KB [256 rows][64 cols]
#pragma unroll 1
  for (int rnd = 0; rnd < 2; ++rnd) {
    if (wrN == 2 + rnd) {  // U waves dump
#pragma unroll
      for (int mi = 0; mi < 8; ++mi)
#pragma unroll
        for (int ni = 0; ni < 4; ++ni)
#pragma unroll
          for (int r = 0; r < 4; ++r)
            ex[(wrM * 128 + mi * 16 + lk * 4 + r) * 64 + ni * 16 + lrow] = acc[mi][ni][r];
    }
    __syncthreads();
    if (wrN == rnd) {  // G waves consume + store h
#pragma unroll
      for (int mi = 0; mi < 8; ++mi)
#pragma unroll
        for (int ni = 0; ni < 4; ++ni)
#pragma unroll
          for (int r = 0; r < 4; ++r) {
            int grow = wrM * 128 + mi * 16 + lk * 4 + r;
            if (grow < vr) {
              float g = acc[mi][ni][r];
              float u = ex[grow * 64 + ni * 16 + lrow];
              float hv = g / (1.f + __expf(-g)) * u;
              int col = ib + rnd * 64 + ni * 16 + lrow;
              h_buf[(size_t)(off + mt * 256 + grow) * I_DIM + col] = f2bf(hv);
            }
          }
    }
    __syncthreads();
  }
}

// ================= stage 2: y += route_w * (h Wd^T) =================
// BM=256, B-tile = 128 Wd rows (H-cols), BK=32, 8 waves 2M x 4N (wave 128x32).
#define DN_NIT 24

__global__ __launch_bounds__(512, 4) void gemm_down_kernel(
    const ushort_t* __restrict__ h_buf, const float* __restrict__ wd,
    const int* __restrict__ offsets, const int* __restrict__ counts,
    const int* __restrict__ pair_token, const float* __restrict__ pair_w,
    const int* __restrict__ tile_list, const int* __restrict__ n_tiles,
    float* __restrict__ y) {
  int idx = xcd_decode(blockIdx.x, (*n_tiles) * 8);
  if (idx < 0) return;
  int tl = idx >> 3, nt = idx & 7;
  int ent = tile_list[tl];
  int e = ent >> 2, mt = ent & 3;
  int ne = counts[e], off = offsets[e];
  int hb = nt * 128;
  int vr = ne - mt * 256;
  if (vr <= 0) return;
  if (vr > 256) vr = 256;

  __shared__ __align__(16) char L[51200];  // A 2x16K @0, B 2x8K @32K, tok/pw @48K
  ushort_t* AsB = (ushort_t*)L;
  ushort_t* BlB = (ushort_t*)(L + 32768);
  int* sTok = (int*)(L + 49152);
  float* sPw = (float*)(L + 50176);

  const int tid = threadIdx.x;
  const int lane = tid & 63;
  const int wid = tid >> 6;
  const int wrM = wid >> 2, wrN = wid & 3;
  const int lrow = lane & 15, lk = lane >> 4;

  if (tid < 256) {
    int p = mt * 256 + tid;
    int ix = off + (p < ne ? p : ne - 1);
    sTok[tid] = pair_token[ix];
    sPw[tid] = pair_w[ix];
  }
  __syncthreads();

  const ushort_t* asrc[2];
  int adst[2];
#pragma unroll
  for (int j = 0; j < 2; ++j) {
    int p = j * 512 + tid;
    int row = p >> 2, c = p & 3;
    int pr = mt * 256 + row;
    int hr = off + (pr < ne ? pr : ne - 1);
    asrc[j] = h_buf + (size_t)hr * I_DIM + ((c ^ ((row >> 1) & 3)) << 3);
    adst[j] = (j * 512 + wid * 64) * 8;
  }
  // B glb: 512 chunks, 1/thread
  const int brow = tid >> 2, csl = tid & 3;
  const float* bsrc = wd + ((size_t)e * H_DIM + hb + brow) * I_DIM + ((csl ^ 0) * 8);
  const int bd = (brow * 4 + (csl ^ ((brow >> 1) & 3))) * 8;
  // note: source chunk = csl (logical), dest slot swizzled

  const bool wact = (wrM * 128) < vr;

  f32x4 acc[8][2];
#pragma unroll
  for (int mi = 0; mi < 8; ++mi)
#pragma unroll
    for (int ni = 0; ni < 2; ++ni) acc[mi][ni] = f32x4{0.f, 0.f, 0.f, 0.f};

#define DN_ADMA(NB, K0)                                           \
  do {                                                            \
    async16(&AsB[(NB) * 8192 + adst[0]], asrc[0] + (K0));         \
    async16(&AsB[(NB) * 8192 + adst[1]], asrc[1] + (K0));         \
  } while (0)

#define DN_AF(AB, MI)                                                        \
  do {                                                                       \
    int R0 = wrM * 128 + (MI) * 16 + lrow;                                   \
    int R1 = R0 + 16;                                                        \
    af0 = *(const u16x8*)&AsB[(AB) * 8192 + R0 * 32 + ((lk ^ ((R0 >> 1) & 3)) << 3)]; \
    af1 = *(const u16x8*)&AsB[(AB) * 8192 + R1 * 32 + ((lk ^ ((R1 >> 1) & 3)) << 3)]; \
  } while (0)

#define DN_MFMA2(MI)                                                         \
  _Pragma("unroll") for (int ni = 0; ni < 2; ++ni) {                         \
    acc[MI][ni] = __builtin_amdgcn_mfma_f32_16x16x32_bf16(                   \
        __builtin_bit_cast(bf16x8, af0), __builtin_bit_cast(bf16x8, bf[ni]), \
        acc[MI][ni], 0, 0, 0);                                               \
    acc[(MI) + 1][ni] = __builtin_amdgcn_mfma_f32_16x16x32_bf16(             \
        __builtin_bit_cast(bf16x8, af1), __builtin_bit_cast(bf16x8, bf[ni]), \
        acc[(MI) + 1][ni], 0, 0, 0);                                         \
  }

  // prologue
  DN_ADMA(0, 0);
  {
    f32x4 p0 = *(const f32x4*)(bsrc), p1 = *(const f32x4*)(bsrc + 4);
    *(u16x8*)&BlB[bd] = cvt8b(p0, p1);
  }
  FENCE_LGKM;
  __builtin_amdgcn_s_barrier();

#pragma unroll 1
  for (int t = 0; t < DN_NIT; ++t) {
    const int b = t & 1, nb = b ^ 1;
    const int kn = (t + 1 < DN_NIT) ? (t + 1) * 32 : 0;
    u16x8 bf[2], af0, af1;
    f32x4 br0, br1;
    // phase 0
    br0 = *(const f32x4*)(bsrc + kn);
    br1 = *(const f32x4*)(bsrc + kn + 4);
    asm volatile("s_waitcnt vmcnt(2)" ::: "memory");
    __builtin_amdgcn_sched_barrier(0);
    __builtin_amdgcn_s_barrier();
    if (wact) {
#pragma unroll
      for (int ni = 0; ni < 2; ++ni) {
        int Rb = wrN * 32 + ni * 16 + lrow;
        bf[ni] = *(const u16x8*)&BlB[b * 4096 + Rb * 32 + ((lk ^ ((Rb >> 1) & 3)) << 3)];
      }
      DN_AF(b, 0);
    }
    FENCE_LGKM;
    __builtin_amdgcn_s_setprio(1);
    if (wact) { DN_MFMA2(0); }
    __builtin_amdgcn_s_setprio(0);
    __builtin_amdgcn_s_barrier();
    // phase 1
    if (wact) DN_AF(b, 2);
    FENCE_LGKM;
    __builtin_amdgcn_s_setprio(1);
    if (wact) { DN_MFMA2(2); }
    __builtin_amdgcn_s_setprio(0);
    __builtin_amdgcn_s_barrier();
    // phase 2
    DN_ADMA(nb, kn);
    if (wact) DN_AF(b, 4);
    FENCE_LGKM;
    __builtin_amdgcn_s_setprio(1);
    if (wact) { DN_MFMA2(4); }
    __builtin_amdgcn_s_setprio(0);
    __builtin_amdgcn_s_barrier();
    // phase 3
    *(u16x8*)&BlB[nb * 4096 + bd] = cvt8b(br0, br1);
    if (wact) DN_AF(b, 6);
    FENCE_LGKM;
    __builtin_amdgcn_s_setprio(1);
    if (wact) { DN_MFMA2(6); }
    __builtin_amdgcn_s_setprio(0);
    __builtin_amdgcn_s_barrier();
  }
#undef DN_ADMA
#undef DN_AF
#undef DN_MFMA2

  // epilogue: scale + atomic accumulate
#pragma unroll
  for (int mi = 0; mi < 8; ++mi)
#pragma unroll
    for (int ni = 0; ni < 2; ++ni)
#pragma unroll
      for (int r = 0; r < 4; ++r) {
        int grow = wrM * 128 + mi * 16 + lk * 4 + r;
        if (grow < vr) {
          int col = hb + wrN * 32 + ni * 16 + lrow;
          float val = acc[mi][ni][r] * sPw[grow];
          unsafeAtomicAdd(&y[(size_t)sTok[grow] * H_DIM + col], val);
        }
      }
}

extern "C" void kernel_launch(void* const* d_in, const int* in_sizes, int n_in,
                              void* d_out, int out_size, void* d_ws, size_t ws_size,
                              hipStream_t stream) {
  const float* x  = (const float*)d_in[0];
  const float* wr = (const float*)d_in[1];
  const float* wg = (const float*)d_in[2];
  const float* wu = (const float*)d_in[3];
  const float* wd = (const float*)d_in[4];
  float* y = (float*)d_out;

  char* ws = (char*)d_ws;
  int* counts    = (int*)(ws + 0);
  int* offsets   = (int*)(ws + 256);
  int* cursor    = (int*)(ws + 512);
  int* n_tiles   = (int*)(ws + 768);
  int* tile_list = (int*)(ws + 1024);
  int*   topk_id    = (int*)(ws + 2048);
  float* topk_w     = (float*)(ws + 2048 + 1 * 65536);
  int*   pair_token = (int*)(ws + 2048 + 2 * 65536);
  float* pair_w     = (float*)(ws + 2048 + 3 * 65536);
  ushort_t* h_buf = (ushort_t*)(ws + 2048 + 4 * 65536);  // 25.2 MB
  ushort_t* xb = (ushort_t*)(ws + 2048 + 4 * 65536 + (size_t)T_TOK * I_DIM * K_TOP * 2);  // 4 MB

  hipMemsetAsync(counts, 0, 256, stream);
  hipMemsetAsync(y, 0, (size_t)T_TOK * H_DIM * sizeof(float), stream);

  xcast_kernel<<<(T_TOK * H_DIM / 8) / 256, 256, 0, stream>>>(x, xb);
  router_kernel<<<T_TOK / 4, 64, 0, stream>>>(x, wr, topk_id, topk_w, counts);
  scan_kernel<<<1, 64, 0, stream>>>(counts, offsets, cursor, tile_list, n_tiles);
  build_kernel<<<(T_TOK * K_TOP) / 256, 256, 0, stream>>>(topk_id, topk_w, cursor, pair_token, pair_w);
  gemm_gu_kernel<<<128 * 6, 512, 0, stream>>>(
      xb, wg, wu, offsets, counts, pair_token, tile_list, n_tiles, h_buf);
  gemm_down_kernel<<<128 * 8, 512, 0, stream>>>(
      h_buf, wd, offsets, counts, pair_token, pair_w, tile_list, n_tiles, y);
}

// Round 13
// 412.674 us; speedup vs baseline: 1.3494x; 1.3494x over previous
//
#include <hip/hip_runtime.h>
#include <hip/hip_bf16.h>
#include <cstdint>
#include <cstddef>

// Qwen3 MoE layer: T=2048 tokens, H=1024 hidden, E=64 experts, I=768, top-K=8
#define T_TOK 2048
#define H_DIM 1024
#define E_NUM 64
#define I_DIM 768
#define K_TOP 8

typedef __attribute__((ext_vector_type(8))) __bf16 bf16x8;
typedef __attribute__((ext_vector_type(8))) unsigned short u16x8;
typedef __attribute__((ext_vector_type(4))) float f32x4;
typedef unsigned short ushort_t;

__device__ __forceinline__ unsigned short f2bf(float f) {
  uint32_t u = __builtin_bit_cast(uint32_t, f);
  u += 0x7fffu + ((u >> 16) & 1u);
  return (unsigned short)(u >> 16);
}

__device__ __forceinline__ u16x8 cvt8b(f32x4 a, f32x4 b) {
  bf16x8 r;
  r[0] = (__bf16)a[0]; r[1] = (__bf16)a[1]; r[2] = (__bf16)a[2]; r[3] = (__bf16)a[3];
  r[4] = (__bf16)b[0]; r[5] = (__bf16)b[1]; r[6] = (__bf16)b[2]; r[7] = (__bf16)b[3];
  return __builtin_bit_cast(u16x8, r);
}

// async 16B global -> LDS; dest = wave-uniform base (HW adds lane*16)
__device__ __forceinline__ void async16(const void* l, const void* g) {
  __builtin_amdgcn_global_load_lds(
      (const __attribute__((address_space(1))) unsigned int*)g,
      (__attribute__((address_space(3))) unsigned int*)l, 16, 0, 0);
}

// Bijective XCD-contiguous decode over the ACTIVE index space [0, n_act)
__device__ __forceinline__ int xcd_decode(int wg0, int n_act) {
  int q = n_act >> 3, r = n_act & 7;
  int xcd = wg0 & 7, rank = wg0 >> 3;
  int cnt = q + (xcd < r ? 1 : 0);
  if (rank >= cnt) return -1;
  return (xcd < r ? xcd * (q + 1) : r * (q + 1) + (xcd - r) * q) + rank;
}

// ---------------- x f32 -> bf16 pre-cast ----------------
__global__ __launch_bounds__(256) void xcast_kernel(const float* __restrict__ x,
                                                    ushort_t* __restrict__ xb) {
  int i = blockIdx.x * 256 + threadIdx.x;
  const f32x4* s = (const f32x4*)(x + (size_t)i * 8);
  *(u16x8*)(xb + (size_t)i * 8) = cvt8b(s[0], s[1]);
}

// ---------------- router: 4 tokens/block ----------------
__global__ __launch_bounds__(64) void router_kernel(
    const float* __restrict__ x, const float* __restrict__ wr,
    int* __restrict__ topk_id, float* __restrict__ topk_w,
    int* __restrict__ counts) {
  const int t0 = blockIdx.x * 4;
  const int e = threadIdx.x;
  const float4* wv = (const float4*)(wr + (size_t)e * H_DIM);
  const float4* xv0 = (const float4*)(x + (size_t)t0 * H_DIM);
  const float4* xv1 = (const float4*)(x + (size_t)(t0 + 1) * H_DIM);
  const float4* xv2 = (const float4*)(x + (size_t)(t0 + 2) * H_DIM);
  const float4* xv3 = (const float4*)(x + (size_t)(t0 + 3) * H_DIM);
  float acc0 = 0.f, acc1 = 0.f, acc2 = 0.f, acc3 = 0.f;
#pragma unroll 4
  for (int i = 0; i < H_DIM / 4; ++i) {
    float4 b = wv[i];
    float4 a0 = xv0[i], a1 = xv1[i], a2 = xv2[i], a3 = xv3[i];
    acc0 = fmaf(a0.x, b.x, fmaf(a0.y, b.y, fmaf(a0.z, b.z, fmaf(a0.w, b.w, acc0))));
    acc1 = fmaf(a1.x, b.x, fmaf(a1.y, b.y, fmaf(a1.z, b.z, fmaf(a1.w, b.w, acc1))));
    acc2 = fmaf(a2.x, b.x, fmaf(a2.y, b.y, fmaf(a2.z, b.z, fmaf(a2.w, b.w, acc2))));
    acc3 = fmaf(a3.x, b.x, fmaf(a3.y, b.y, fmaf(a3.z, b.z, fmaf(a3.w, b.w, acc3))));
  }
  float accs[4] = {acc0, acc1, acc2, acc3};
#pragma unroll 1
  for (int tt = 0; tt < 4; ++tt) {
    int t = t0 + tt;
    float acc = accs[tt];
    float m = acc;
    for (int o = 32; o; o >>= 1) m = fmaxf(m, __shfl_xor(m, o));
    float p = __expf(acc - m);
    float s = p;
    for (int o = 32; o; o >>= 1) s += __shfl_xor(s, o);
    p /= s;
    float v = p;
    int sid = 0;
    float sw = 0.f;
    for (int k = 0; k < K_TOP; ++k) {
      float bv = v;
      int bi = e;
      for (int o = 32; o; o >>= 1) {
        float ov = __shfl_xor(bv, o);
        int oi = __shfl_xor(bi, o);
        if (ov > bv || (ov == bv && oi < bi)) { bv = ov; bi = oi; }
      }
      if (e == k) { sid = bi; sw = bv; }
      if (e == bi) v = -1.f;
    }
    float ssum = (e < K_TOP) ? sw : 0.f;
    for (int o = 32; o; o >>= 1) ssum += __shfl_xor(ssum, o);
    if (e < K_TOP) {
      topk_id[t * K_TOP + e] = sid;
      topk_w[t * K_TOP + e] = sw / ssum;
      atomicAdd(&counts[sid], 1);
    }
  }
}

// ---------------- scan: offsets + tile list (BM=128, max 3 tiles/expert) ----------------
__global__ __launch_bounds__(64) void scan_kernel(
    const int* __restrict__ counts, int* __restrict__ offsets,
    int* __restrict__ cursor, int* __restrict__ tile_list,
    int* __restrict__ n_tiles) {
  int e = threadIdx.x;
  int ne = counts[e];
  int x = ne;
  for (int o = 1; o < 64; o <<= 1) {
    int v = __shfl_up(x, o);
    if (e >= o) x += v;
  }
  int excl = x - ne;
  offsets[e] = excl;
  cursor[e] = excl;
  int ntl = (ne + 127) >> 7;
  if (ntl > 3) ntl = 3;
  int y2 = ntl;
  for (int o = 1; o < 64; o <<= 1) {
    int v = __shfl_up(y2, o);
    if (e >= o) y2 += v;
  }
  int texcl = y2 - ntl;
  for (int m = 0; m < ntl; ++m) tile_list[texcl + m] = (e << 2) | m;
  if (e == 63) *n_tiles = texcl + ntl;
}

__global__ __launch_bounds__(256) void build_kernel(
    const int* __restrict__ topk_id, const float* __restrict__ topk_w,
    int* __restrict__ cursor, int* __restrict__ pair_token, float* __restrict__ pair_w) {
  int i = blockIdx.x * 256 + threadIdx.x;
  int t = i >> 3;
  int e = topk_id[i];
  int pos = atomicAdd(&cursor[e], 1);
  pair_token[pos] = t;
  pair_w[pos] = topk_w[i];
}

// bf16 LDS rows: 32 bf16 = 4 chunks of 16B; chunk slot = c ^ ((row>>1)&3)

// ================= stage 1: h = silu(X Wg^T) * (X Wu^T) =================
// m97-clone: BM=128, BN=64 (G and U), BK=32, 256 thr (4 waves 2Mx2N),
// single-buffer 16.5 KB LDS, two __syncthreads per iter, 3 blocks/CU (TLP).
#define GU_NIT 32

__global__ __launch_bounds__(256, 3) void gemm_gu_kernel(
    const ushort_t* __restrict__ xb, const float* __restrict__ wg,
    const float* __restrict__ wu, const int* __restrict__ offsets,
    const int* __restrict__ counts, const int* __restrict__ pair_token,
    const int* __restrict__ tile_list, const int* __restrict__ n_tiles,
    ushort_t* __restrict__ h_buf) {
  int idx = xcd_decode(blockIdx.x, (*n_tiles) * 12);
  if (idx < 0) return;
  int tl = idx / 12, nt = idx - tl * 12;
  int ent = tile_list[tl];
  int e = ent >> 2, mt = ent & 3;
  int ne = counts[e], off = offsets[e];
  int ib = nt * 64;
  int vr = ne - mt * 128;
  if (vr <= 0) return;
  if (vr > 128) vr = 128;

  __shared__ __align__(16) ushort_t Xs[128 * 32];  // 8 KB
  __shared__ __align__(16) ushort_t Gs[64 * 32];   // 4 KB
  __shared__ __align__(16) ushort_t Us[64 * 32];   // 4 KB
  __shared__ int sTok[128];

  const int tid = threadIdx.x;
  const int lane = tid & 63;
  const int wid = tid >> 6;  // 0..3
  if (tid < 128) {
    int p = mt * 128 + tid;
    sTok[tid] = pair_token[off + (p < ne ? p : ne - 1)];
  }
  __syncthreads();

  // X DMA: 512 chunks of 16B, 2/thread; linear dest + inverse-swizzled src
  const ushort_t* xsrc[2];
  int xdst[2];
#pragma unroll
  for (int j = 0; j < 2; ++j) {
    int p = j * 256 + tid;
    int row = p >> 2, c = p & 3;
    xsrc[j] = xb + (size_t)sTok[row] * H_DIM + ((c ^ ((row >> 1) & 3)) << 3);
    xdst[j] = (j * 256 + wid * 64) * 8;  // wave-uniform base (elems)
  }
  // W staging: thread -> G/U row tid>>2, bf16-chunk c=tid&3 (2 f32x4 each)
  const int wrow = tid >> 2, wc = tid & 3;
  const float* gsrc = wg + ((size_t)e * I_DIM + ib + wrow) * H_DIM + wc * 8;
  const float* usrc = wu + ((size_t)e * I_DIM + ib + wrow) * H_DIM + wc * 8;
  const int wdst = (wrow * 4 + (wc ^ ((wrow >> 1) & 3))) * 8;

  const int wrM = wid >> 1, wrN = wid & 1;  // 2M x 2N
  const int lrow = lane & 15, lk = lane >> 4;
  const bool wact = (wrM * 64) < vr;

  f32x4 accG[4][2], accU[4][2];
#pragma unroll
  for (int mi = 0; mi < 4; ++mi)
#pragma unroll
    for (int ni = 0; ni < 2; ++ni) {
      accG[mi][ni] = f32x4{0.f, 0.f, 0.f, 0.f};
      accU[mi][ni] = f32x4{0.f, 0.f, 0.f, 0.f};
    }

#pragma unroll 1
  for (int k = 0; k < GU_NIT; ++k) {
    const int k0 = k * 32;
    // stage (LDS free: previous iter's trailing barrier)
    async16(&Xs[xdst[0]], xsrc[0] + k0);
    async16(&Xs[xdst[1]], xsrc[1] + k0);
    {
      f32x4 g0 = *(const f32x4*)(gsrc + k0);
      f32x4 g1 = *(const f32x4*)(gsrc + k0 + 4);
      f32x4 u0 = *(const f32x4*)(usrc + k0);
      f32x4 u1 = *(const f32x4*)(usrc + k0 + 4);
      *(u16x8*)&Gs[wdst] = cvt8b(g0, g1);
      *(u16x8*)&Us[wdst] = cvt8b(u0, u1);
    }
    __syncthreads();  // drains vmcnt+lgkmcnt: tile ready
    if (wact) {
      bf16x8 af[4];
#pragma unroll
      for (int mi = 0; mi < 4; ++mi) {
        int r = wrM * 64 + mi * 16 + lrow;
        af[mi] = __builtin_bit_cast(
            bf16x8, *(const u16x8*)&Xs[r * 32 + ((lk ^ ((r >> 1) & 3)) << 3)]);
      }
#pragma unroll
      for (int ni = 0; ni < 2; ++ni) {
        int br = wrN * 32 + ni * 16 + lrow;
        int ci = br * 32 + ((lk ^ ((br >> 1) & 3)) << 3);
        bf16x8 bg = __builtin_bit_cast(bf16x8, *(const u16x8*)&Gs[ci]);
        bf16x8 bu = __builtin_bit_cast(bf16x8, *(const u16x8*)&Us[ci]);
#pragma unroll
        for (int mi = 0; mi < 4; ++mi) {
          accG[mi][ni] = __builtin_amdgcn_mfma_f32_16x16x32_bf16(af[mi], bg, accG[mi][ni], 0, 0, 0);
          accU[mi][ni] = __builtin_amdgcn_mfma_f32_16x16x32_bf16(af[mi], bu, accU[mi][ni], 0, 0, 0);
        }
      }
    }
    __syncthreads();  // all reads done before next stage
  }

  // epilogue: SwiGLU + bf16 store (C/D: row=(lane>>4)*4+reg, col=lane&15)
#pragma unroll
  for (int mi = 0; mi < 4; ++mi)
#pragma unroll
    for (int ni = 0; ni < 2; ++ni)
#pragma unroll
      for (int r = 0; r < 4; ++r) {
        int grow = wrM * 64 + mi * 16 + lk * 4 + r;
        if (grow < vr) {
          int col = ib + wrN * 32 + ni * 16 + lrow;
          float g = accG[mi][ni][r], u = accU[mi][ni][r];
          float hv = g / (1.f + __expf(-g)) * u;
          h_buf[(size_t)(off + mt * 128 + grow) * I_DIM + col] = f2bf(hv);
        }
      }
}

// ================= stage 2: y += route_w * (h Wd^T) =================
// m97-clone: BM=128, BN=128, BK=32, 256 thr (4 waves 2Mx2N, wave 64x64),
// single-buffer 17 KB LDS, 3 blocks/CU.
#define DN_NIT 24

__global__ __launch_bounds__(256, 3) void gemm_down_kernel(
    const ushort_t* __restrict__ h_buf, const float* __restrict__ wd,
    const int* __restrict__ offsets, const int* __restrict__ counts,
    const int* __restrict__ pair_token, const float* __restrict__ pair_w,
    const int* __restrict__ tile_list, const int* __restrict__ n_tiles,
    float* __restrict__ y) {
  int idx = xcd_decode(blockIdx.x, (*n_tiles) * 8);
  if (idx < 0) return;
  int tl = idx >> 3, nt = idx & 7;
  int ent = tile_list[tl];
  int e = ent >> 2, mt = ent & 3;
  int ne = counts[e], off = offsets[e];
  int hb = nt * 128;
  int vr = ne - mt * 128;
  if (vr <= 0) return;
  if (vr > 128) vr = 128;

  __shared__ __align__(16) ushort_t Ah[128 * 32];  // 8 KB
  __shared__ __align__(16) ushort_t Bs[128 * 32];  // 8 KB
  __shared__ int sTok[128];
  __shared__ float sPw[128];

  const int tid = threadIdx.x;
  const int lane = tid & 63;
  const int wid = tid >> 6;
  if (tid < 128) {
    int p = mt * 128 + tid;
    int ix = off + (p < ne ? p : ne - 1);
    sTok[tid] = pair_token[ix];
    sPw[tid] = pair_w[ix];
  }
  __syncthreads();

  const ushort_t* asrc[2];
  int adst[2];
#pragma unroll
  for (int j = 0; j < 2; ++j) {
    int p = j * 256 + tid;
    int row = p >> 2, c = p & 3;
    int pr = mt * 128 + row;
    int hr = off + (pr < ne ? pr : ne - 1);
    asrc[j] = h_buf + (size_t)hr * I_DIM + ((c ^ ((row >> 1) & 3)) << 3);
    adst[j] = (j * 256 + wid * 64) * 8;
  }
  // B staging: 128 rows x 4 bf16-chunks = 512 chunks, 2/thread (row tid>>1)
  const int brow = tid >> 1, bc0 = (tid & 1) * 2, bc1 = bc0 + 1;
  const float* bsrc = wd + ((size_t)e * H_DIM + hb + brow) * I_DIM + bc0 * 8;
  const int bdst0 = (brow * 4 + (bc0 ^ ((brow >> 1) & 3))) * 8;
  const int bdst1 = (brow * 4 + (bc1 ^ ((brow >> 1) & 3))) * 8;

  const int wrM = wid >> 1, wrN = wid & 1;
  const int lrow = lane & 15, lk = lane >> 4;
  const bool wact = (wrM * 64) < vr;

  f32x4 acc[4][4];
#pragma unroll
  for (int mi = 0; mi < 4; ++mi)
#pragma unroll
    for (int ni = 0; ni < 4; ++ni) acc[mi][ni] = f32x4{0.f, 0.f, 0.f, 0.f};

#pragma unroll 1
  for (int k = 0; k < DN_NIT; ++k) {
    const int k0 = k * 32;
    async16(&Ah[adst[0]], asrc[0] + k0);
    async16(&Ah[adst[1]], asrc[1] + k0);
    {
      f32x4 b0 = *(const f32x4*)(bsrc + k0);
      f32x4 b1 = *(const f32x4*)(bsrc + k0 + 4);
      f32x4 b2 = *(const f32x4*)(bsrc + k0 + 8);
      f32x4 b3 = *(const f32x4*)(bsrc + k0 + 12);
      *(u16x8*)&Bs[bdst0] = cvt8b(b0, b1);
      *(u16x8*)&Bs[bdst1] = cvt8b(b2, b3);
    }
    __syncthreads();
    if (wact) {
      bf16x8 af[4];
#pragma unroll
      for (int mi = 0; mi < 4; ++mi) {
        int r = wrM * 64 + mi * 16 + lrow;
        af[mi] = __builtin_bit_cast(
            bf16x8, *(const u16x8*)&Ah[r * 32 + ((lk ^ ((r >> 1) & 3)) << 3)]);
      }
#pragma unroll
      for (int ni = 0; ni < 4; ++ni) {
        int br = wrN * 64 + ni * 16 + lrow;
        bf16x8 bb = __builtin_bit_cast(
            bf16x8, *(const u16x8*)&Bs[br * 32 + ((lk ^ ((br >> 1) & 3)) << 3)]);
#pragma unroll
        for (int mi = 0; mi < 4; ++mi)
          acc[mi][ni] = __builtin_amdgcn_mfma_f32_16x16x32_bf16(af[mi], bb, acc[mi][ni], 0, 0, 0);
      }
    }
    __syncthreads();
  }

  // epilogue: scale + atomic accumulate
#pragma unroll
  for (int mi = 0; mi < 4; ++mi)
#pragma unroll
    for (int ni = 0; ni < 4; ++ni)
#pragma unroll
      for (int r = 0; r < 4; ++r) {
        int grow = wrM * 64 + mi * 16 + lk * 4 + r;
        if (grow < vr) {
          int col = hb + wrN * 64 + ni * 16 + lrow;
          float val = acc[mi][ni][r] * sPw[grow];
          unsafeAtomicAdd(&y[(size_t)sTok[grow] * H_DIM + col], val);
        }
      }
}

extern "C" void kernel_launch(void* const* d_in, const int* in_sizes, int n_in,
                              void* d_out, int out_size, void* d_ws, size_t ws_size,
                              hipStream_t stream) {
  const float* x  = (const float*)d_in[0];
  const float* wr = (const float*)d_in[1];
  const float* wg = (const float*)d_in[2];
  const float* wu = (const float*)d_in[3];
  const float* wd = (const float*)d_in[4];
  float* y = (float*)d_out;

  char* ws = (char*)d_ws;
  int* counts    = (int*)(ws + 0);
  int* offsets   = (int*)(ws + 256);
  int* cursor    = (int*)(ws + 512);
  int* n_tiles   = (int*)(ws + 768);
  int* tile_list = (int*)(ws + 1024);
  int*   topk_id    = (int*)(ws + 2048);
  float* topk_w     = (float*)(ws + 2048 + 1 * 65536);
  int*   pair_token = (int*)(ws + 2048 + 2 * 65536);
  float* pair_w     = (float*)(ws + 2048 + 3 * 65536);
  ushort_t* h_buf = (ushort_t*)(ws + 2048 + 4 * 65536);  // 25.2 MB
  ushort_t* xb = (ushort_t*)(ws + 2048 + 4 * 65536 + (size_t)T_TOK * I_DIM * K_TOP * 2);  // 4 MB

  hipMemsetAsync(counts, 0, 256, stream);
  hipMemsetAsync(y, 0, (size_t)T_TOK * H_DIM * sizeof(float), stream);

  xcast_kernel<<<(T_TOK * H_DIM / 8) / 256, 256, 0, stream>>>(x, xb);
  router_kernel<<<T_TOK / 4, 64, 0, stream>>>(x, wr, topk_id, topk_w, counts);
  scan_kernel<<<1, 64, 0, stream>>>(counts, offsets, cursor, tile_list, n_tiles);
  build_kernel<<<(T_TOK * K_TOP) / 256, 256, 0, stream>>>(topk_id, topk_w, cursor, pair_token, pair_w);
  // grids cover worst case (3 tiles/expert); inactive blocks exit via xcd_decode
  gemm_gu_kernel<<<E_NUM * 3 * 12, 256, 0, stream>>>(
      xb, wg, wu, offsets, counts, pair_token, tile_list, n_tiles, h_buf);
  gemm_down_kernel<<<E_NUM * 3 * 8, 256, 0, stream>>>(
      h_buf, wd, offsets, counts, pair_token, pair_w, tile_list, n_tiles, y);
}